// Round 16
// baseline (119.601 us; speedup 1.0000x reference)
//
#include <hip/hip_runtime.h>

// BERT-CRF NER, three kernels.
//  K1 feats: byte-identical to round 14 (F ~= 39us, near L3-warm floor).
//  K2 vit_fwd: phase-1 recurrence only. grid 16 x block 1024 = 16 waves/CU
//     -> 4 independent chains per SIMD interleave, hiding the ~5cyc/instr
//     dependent-issue latency a solo wave pays (r12/r15 evidence: 423cyc/step
//     solo). Math instruction-identical to r4 phase 1; ld history stored
//     fire-and-forget to global ldh[b][t][16]; ft double-buffered from
//     featsT (global, L2-warm). Zero LDS, zero barriers.
//  K3 vit_post: r4 viterbi minus phase 1 — stages lds_ld from ldh, then
//     phases 2-5 byte-identical (psi, ancestor maps, backtrace, softmax).
// B=256, T=256, H=768, L=13, START=11.
// Outputs (float32): [0..255] max_p/T; [256..65791] path.

#define NEGV (-10000.0f)

#define DPP_ADD(v, ctrl, rmask)                                               \
  v += __int_as_float(__builtin_amdgcn_update_dpp(                            \
      0, __float_as_int(v), (ctrl), (rmask), 0xF, true));

#define DPP_REDUCE64(v)                                                       \
  DPP_ADD(v, 0x111, 0xF)  /* row_shr:1  */                                    \
  DPP_ADD(v, 0x112, 0xF)  /* row_shr:2  */                                    \
  DPP_ADD(v, 0x114, 0xF)  /* row_shr:4  */                                    \
  DPP_ADD(v, 0x118, 0xF)  /* row_shr:8  */                                    \
  DPP_ADD(v, 0x142, 0xA)  /* row_bcast:15 */                                  \
  DPP_ADD(v, 0x143, 0xC)  /* row_bcast:31 */

// ---------------------------------------------------------------- kernel 1 --
__global__ __launch_bounds__(256)
__attribute__((amdgpu_waves_per_eu(2, 2)))
void feats_kernel(
    const float* __restrict__ X,      // [65536, 768]
    const float* __restrict__ W,      // [13, 768]
    const float* __restrict__ bias,   // [13]
    float* __restrict__ featsT)       // [13][65536]
{
  const int tid = threadIdx.x;
  const int w = tid >> 6, l = tid & 63;
  const long row0 = (long)blockIdx.x * 128 + w * 32;

  float wreg[13][12];
  #pragma unroll
  for (int col = 0; col < 13; ++col) {
    #pragma unroll
    for (int j = 0; j < 3; ++j) {
      float4 v = *reinterpret_cast<const float4*>(W + col * 768 + 256 * j + 4 * l);
      wreg[col][4 * j + 0] = v.x; wreg[col][4 * j + 1] = v.y;
      wreg[col][4 * j + 2] = v.z; wreg[col][4 * j + 3] = v.w;
    }
  }
  float bs[13];
  #pragma unroll
  for (int c = 0; c < 13; ++c) bs[c] = bias[c];

  const float* xp = X + row0 * 768 + 4 * l;

  float4 buf[4][3];
  #pragma unroll
  for (int i = 0; i < 4; ++i) {
    buf[i][0] = *reinterpret_cast<const float4*>(xp + i * 768);
    buf[i][1] = *reinterpret_cast<const float4*>(xp + i * 768 + 256);
    buf[i][2] = *reinterpret_cast<const float4*>(xp + i * 768 + 512);
  }

  #pragma unroll 4
  for (int r = 0; r < 32; ++r) {
    const int s = r & 3;
    const float4 b0 = buf[s][0], b1 = buf[s][1], b2 = buf[s][2];

    float acc[13];
    #pragma unroll
    for (int c = 0; c < 13; ++c) acc[c] = 0.0f;
    #pragma unroll
    for (int col = 0; col < 13; ++col) {
      acc[col] = fmaf(b0.x, wreg[col][0],  acc[col]);
      acc[col] = fmaf(b0.y, wreg[col][1],  acc[col]);
      acc[col] = fmaf(b0.z, wreg[col][2],  acc[col]);
      acc[col] = fmaf(b0.w, wreg[col][3],  acc[col]);
      acc[col] = fmaf(b1.x, wreg[col][4],  acc[col]);
      acc[col] = fmaf(b1.y, wreg[col][5],  acc[col]);
      acc[col] = fmaf(b1.z, wreg[col][6],  acc[col]);
      acc[col] = fmaf(b1.w, wreg[col][7],  acc[col]);
      acc[col] = fmaf(b2.x, wreg[col][8],  acc[col]);
      acc[col] = fmaf(b2.y, wreg[col][9],  acc[col]);
      acc[col] = fmaf(b2.z, wreg[col][10], acc[col]);
      acc[col] = fmaf(b2.w, wreg[col][11], acc[col]);
    }

    #pragma unroll
    for (int c = 0; c < 13; ++c) {
      DPP_REDUCE64(acc[c])
    }

    if (l == 63) {
      #pragma unroll
      for (int c = 0; c < 13; ++c)
        featsT[(long)c * 65536 + row0 + r] = acc[c] + bs[c];
    }

    {
      const int pr = (r + 4 < 32) ? (r + 4) : 31;
      const float* xn = xp + pr * 768;
      buf[s][0] = *reinterpret_cast<const float4*>(xn);
      buf[s][1] = *reinterpret_cast<const float4*>(xn + 256);
      buf[s][2] = *reinterpret_cast<const float4*>(xn + 512);
    }
  }
}

// ---------------------------------------------------------------- kernel 2 --
// One wave per batch; 16 waves per block -> 4 chains/SIMD co-resident.
// Recurrence instruction-identical to r4 phase 1; zero LDS/barriers.
__global__ __launch_bounds__(1024) void vit_fwd(
    const float* __restrict__ featsT,  // [13][65536]
    const float* __restrict__ trans,   // [13,13]
    float* __restrict__ ldh)           // [256][256][16] ld history
{
  const int wv = threadIdx.x >> 6;
  const int lane = threadIdx.x & 63;
  const int b = blockIdx.x * 16 + wv;

  float tr[13];
  #pragma unroll
  for (int f = 0; f < 13; ++f)
    tr[f] = (lane < 13) ? trans[lane * 13 + f] : -1.0e30f;

  const int toc = (lane < 13) ? lane : 0;
  const float* frow = featsT + (long)toc * 65536 + b * 256;
  float* lh = ldh + (long)b * 4096;

  float ld = (lane == 11) ? 0.0f : NEGV;  // START = 11
  if (lane < 13) lh[lane] = ld;           // t = 0

  float4 F[4], Fn[4];
  #pragma unroll
  for (int q = 0; q < 4; ++q)
    F[q] = *reinterpret_cast<const float4*>(frow + 4 * q);

  #pragma unroll 1
  for (int g = 0; g < 16; ++g) {
    if (g < 15) {
      #pragma unroll
      for (int q = 0; q < 4; ++q)
        Fn[q] = *reinterpret_cast<const float4*>(frow + (g + 1) * 16 + 4 * q);
    }
    const int kLo = (g == 0) ? 1 : 0;     // skip t = 0
    #pragma unroll
    for (int k = 0; k < 16; ++k) {
      if (k < kLo) continue;
      const int t = g * 16 + k;
      float c[13];
      #pragma unroll
      for (int f = 0; f < 13; ++f) {
        float lf = __uint_as_float(
            __builtin_amdgcn_readlane(__float_as_uint(ld), f));
        c[f] = tr[f] + lf;
      }
      float p0 = fmaxf(fmaxf(c[0], c[1]), c[2]);
      float p1 = fmaxf(fmaxf(c[3], c[4]), c[5]);
      float p2 = fmaxf(fmaxf(c[6], c[7]), c[8]);
      float p3 = fmaxf(fmaxf(c[9], c[10]), c[11]);
      float m  = fmaxf(fmaxf(fmaxf(p0, p1), p2), fmaxf(p3, c[12]));

      const float4 fq = F[k >> 2];
      const float ft = ((k & 3) == 0) ? fq.x : ((k & 3) == 1) ? fq.y
                      : ((k & 3) == 2) ? fq.z : fq.w;
      ld = m + ft;
      if (lane < 13) lh[t * 16 + lane] = ld;  // fire-and-forget
    }
    #pragma unroll
    for (int q = 0; q < 4; ++q) F[q] = Fn[q];
  }
}

// ---------------------------------------------------------------- kernel 3 --
// r4 viterbi minus phase 1: stage lds_ld from ldh, then phases 2-5 verbatim.
__global__ __launch_bounds__(256) void vit_post(
    const float* __restrict__ ldh,     // [256][256][16]
    const float* __restrict__ trans,   // [13,13]
    float* __restrict__ out)           // [256 + 65536]
{
  __shared__ float lds_ld[256 * 16];       // ld_t[to], t = 0..255
  __shared__ float trL[176];               // trans (169 used)
  __shared__ unsigned char psi[256 * 16];  // psi[t][to]
  __shared__ unsigned char Mm[256];        // [16 chunks][16]
  __shared__ unsigned char bnd[16];
  __shared__ unsigned char path[256];

  const int tid = threadIdx.x;
  const int b = blockIdx.x;

  {  // stage ld history: thread tid owns timestep t=tid (64 B, coalesced)
    const float4* src = reinterpret_cast<const float4*>(
        ldh + (long)b * 4096 + tid * 16);
    float4* dst = reinterpret_cast<float4*>(&lds_ld[tid * 16]);
    dst[0] = src[0]; dst[1] = src[1]; dst[2] = src[2]; dst[3] = src[3];
  }
  if (tid < 169) trL[tid] = trans[tid];
  __syncthreads();

  // ---- phase 2: psi in parallel over t ----
  {
    const int to = tid & 15, dtt = tid >> 4;
    if (to < 13) {
      float trr[13];
      #pragma unroll
      for (int f = 0; f < 13; ++f) trr[f] = trL[to * 13 + f];
      for (int t = (dtt == 0 ? 16 : dtt); t < 256; t += 16) {
        const float* lp = &lds_ld[(t - 1) * 16];
        float4 l0 = *reinterpret_cast<const float4*>(lp);
        float4 l1 = *reinterpret_cast<const float4*>(lp + 4);
        float4 l2 = *reinterpret_cast<const float4*>(lp + 8);
        float4 l3 = *reinterpret_cast<const float4*>(lp + 12);
        float c[13] = {trr[0] + l0.x,  trr[1] + l0.y,  trr[2] + l0.z,
                       trr[3] + l0.w,  trr[4] + l1.x,  trr[5] + l1.y,
                       trr[6] + l1.z,  trr[7] + l1.w,  trr[8] + l2.x,
                       trr[9] + l2.y,  trr[10] + l2.z, trr[11] + l2.w,
                       trr[12] + l3.x};
        float best = c[0]; int bf = 0;
        #pragma unroll
        for (int f = 1; f < 13; ++f) {
          bool gt = c[f] > best;              // strict >: first index wins
          best = gt ? c[f] : best;
          bf   = gt ? f : bf;
        }
        psi[t * 16 + to] = (unsigned char)bf;
      }
    }
  }
  __syncthreads();

  // ---- phase 3: ancestor maps ----
  {
    const int sS = tid & 15, g = tid >> 4;
    if (sS < 13) {
      int cur = sS;
      const int tLo = (g == 0) ? 1 : g * 16;
      for (int t = g * 16 + 15; t >= tLo; --t)
        cur = psi[t * 16 + cur];
      Mm[g * 16 + sS] = (unsigned char)cur;
    }
  }
  __syncthreads();

  // ---- phase 4: softmax output + boundary chase ----
  if (tid == 0) {
    const float* lf = &lds_ld[255 * 16];
    float m = lf[0]; int last = 0;
    #pragma unroll
    for (int i = 1; i < 13; ++i)
      if (lf[i] > m) { m = lf[i]; last = i; }   // strict >: first index
    float ssum = 0.0f;
    #pragma unroll
    for (int i = 0; i < 13; ++i) ssum += expf(lf[i] - m);
    out[b] = 1.0f / (256.0f * ssum);            // max(softmax)/T

    int cur = last;
    bnd[15] = (unsigned char)cur;
    #pragma unroll
    for (int cc = 15; cc >= 1; --cc) {
      cur = Mm[cc * 16 + cur];
      bnd[cc - 1] = (unsigned char)cur;
    }
  }
  __syncthreads();

  // ---- phase 5: interior chases ----
  if (tid < 16) {
    int cur = bnd[tid];
    const int tHi = tid * 16 + 15;
    path[tHi] = (unsigned char)cur;
    const int tLo = (tid == 0) ? 1 : tid * 16;
    for (int t = tHi; t >= tLo; --t) {
      cur = psi[t * 16 + cur];
      path[t - 1] = (unsigned char)cur;
    }
  }
  __syncthreads();

  out[256 + (long)b * 256 + tid] = (float)path[tid];
}

// ------------------------------------------------------------------ launch --
extern "C" void kernel_launch(void* const* d_in, const int* in_sizes, int n_in,
                              void* d_out, int out_size, void* d_ws, size_t ws_size,
                              hipStream_t stream) {
  const float* X     = (const float*)d_in[0];
  const float* W     = (const float*)d_in[1];
  const float* bias  = (const float*)d_in[2];
  const float* trans = (const float*)d_in[3];
  float* out    = (float*)d_out;
  float* featsT = (float*)d_ws;                  // 13*65536 floats = 3.4 MB
  float* ldh    = (float*)d_ws + 13 * 65536;     // 256*4096 floats = 4 MB

  feats_kernel<<<512, 256, 0, stream>>>(X, W, bias, featsT);
  vit_fwd<<<16, 1024, 0, stream>>>(featsT, trans, ldh);
  vit_post<<<256, 256, 0, stream>>>(ldh, trans, out);
}

// Round 17
// 88.163 us; speedup vs baseline: 1.3566x; 1.3566x over previous
//
#include <hip/hip_runtime.h>

// BERT-CRF NER, two kernels.
//  K1 feats: byte-identical to round 14 (F ~= 39us, near L3-warm floor).
//  K2 viterbi: r14 kernel with phase 1 de-stalled:
//    - UNGUARDED per-step LDS stores (all 16 lanes; cols 13-15 are junk that
//      phases 2-5 never read) -> no per-step exec-mask save/restore.
//    - chunk 0 peeled -> no runtime `k<kLo` branch in the 15 main chunks.
//    ld for lanes<13 is computed by the identical instruction sequence ->
//    bit-identical results; phases 2-5 byte-identical to r14.
// B=256, T=256, H=768, L=13, START=11.
// Outputs (float32): [0..255] max_p/T; [256..65791] path.

#define NEGV (-10000.0f)

#define DPP_ADD(v, ctrl, rmask)                                               \
  v += __int_as_float(__builtin_amdgcn_update_dpp(                            \
      0, __float_as_int(v), (ctrl), (rmask), 0xF, true));

#define DPP_REDUCE64(v)                                                       \
  DPP_ADD(v, 0x111, 0xF)  /* row_shr:1  */                                    \
  DPP_ADD(v, 0x112, 0xF)  /* row_shr:2  */                                    \
  DPP_ADD(v, 0x114, 0xF)  /* row_shr:4  */                                    \
  DPP_ADD(v, 0x118, 0xF)  /* row_shr:8  */                                    \
  DPP_ADD(v, 0x142, 0xA)  /* row_bcast:15 */                                  \
  DPP_ADD(v, 0x143, 0xC)  /* row_bcast:31 */

// one Viterbi value-step: broadcast ld, add tr, max-tree, add ft, store.
#define VSTEP(t, ft)                                                          \
  {                                                                           \
    float c0  = tr[0]  + __uint_as_float(                                     \
        __builtin_amdgcn_readlane(__float_as_uint(ld), 0));                   \
    float c1  = tr[1]  + __uint_as_float(                                     \
        __builtin_amdgcn_readlane(__float_as_uint(ld), 1));                   \
    float c2  = tr[2]  + __uint_as_float(                                     \
        __builtin_amdgcn_readlane(__float_as_uint(ld), 2));                   \
    float c3  = tr[3]  + __uint_as_float(                                     \
        __builtin_amdgcn_readlane(__float_as_uint(ld), 3));                   \
    float c4  = tr[4]  + __uint_as_float(                                     \
        __builtin_amdgcn_readlane(__float_as_uint(ld), 4));                   \
    float c5  = tr[5]  + __uint_as_float(                                     \
        __builtin_amdgcn_readlane(__float_as_uint(ld), 5));                   \
    float c6  = tr[6]  + __uint_as_float(                                     \
        __builtin_amdgcn_readlane(__float_as_uint(ld), 6));                   \
    float c7  = tr[7]  + __uint_as_float(                                     \
        __builtin_amdgcn_readlane(__float_as_uint(ld), 7));                   \
    float c8  = tr[8]  + __uint_as_float(                                     \
        __builtin_amdgcn_readlane(__float_as_uint(ld), 8));                   \
    float c9  = tr[9]  + __uint_as_float(                                     \
        __builtin_amdgcn_readlane(__float_as_uint(ld), 9));                   \
    float c10 = tr[10] + __uint_as_float(                                     \
        __builtin_amdgcn_readlane(__float_as_uint(ld), 10));                  \
    float c11 = tr[11] + __uint_as_float(                                     \
        __builtin_amdgcn_readlane(__float_as_uint(ld), 11));                  \
    float c12 = tr[12] + __uint_as_float(                                     \
        __builtin_amdgcn_readlane(__float_as_uint(ld), 12));                  \
    float p0 = fmaxf(fmaxf(c0, c1), c2);                                      \
    float p1 = fmaxf(fmaxf(c3, c4), c5);                                      \
    float p2 = fmaxf(fmaxf(c6, c7), c8);                                      \
    float p3 = fmaxf(fmaxf(c9, c10), c11);                                    \
    float m  = fmaxf(fmaxf(fmaxf(p0, p1), p2), fmaxf(p3, c12));               \
    ld = m + (ft);                                                            \
    lds_ld[(t) * 16 + lane] = ld;  /* unguarded: cols 13-15 unused junk */    \
  }

// ---------------------------------------------------------------- kernel 1 --
__global__ __launch_bounds__(256)
__attribute__((amdgpu_waves_per_eu(2, 2)))
void feats_kernel(
    const float* __restrict__ X,      // [65536, 768]
    const float* __restrict__ W,      // [13, 768]
    const float* __restrict__ bias,   // [13]
    float* __restrict__ featsT)       // [13][65536]
{
  const int tid = threadIdx.x;
  const int w = tid >> 6, l = tid & 63;
  const long row0 = (long)blockIdx.x * 128 + w * 32;

  float wreg[13][12];
  #pragma unroll
  for (int col = 0; col < 13; ++col) {
    #pragma unroll
    for (int j = 0; j < 3; ++j) {
      float4 v = *reinterpret_cast<const float4*>(W + col * 768 + 256 * j + 4 * l);
      wreg[col][4 * j + 0] = v.x; wreg[col][4 * j + 1] = v.y;
      wreg[col][4 * j + 2] = v.z; wreg[col][4 * j + 3] = v.w;
    }
  }
  float bs[13];
  #pragma unroll
  for (int c = 0; c < 13; ++c) bs[c] = bias[c];

  const float* xp = X + row0 * 768 + 4 * l;

  float4 buf[4][3];
  #pragma unroll
  for (int i = 0; i < 4; ++i) {
    buf[i][0] = *reinterpret_cast<const float4*>(xp + i * 768);
    buf[i][1] = *reinterpret_cast<const float4*>(xp + i * 768 + 256);
    buf[i][2] = *reinterpret_cast<const float4*>(xp + i * 768 + 512);
  }

  #pragma unroll 4
  for (int r = 0; r < 32; ++r) {
    const int s = r & 3;
    const float4 b0 = buf[s][0], b1 = buf[s][1], b2 = buf[s][2];

    float acc[13];
    #pragma unroll
    for (int c = 0; c < 13; ++c) acc[c] = 0.0f;
    #pragma unroll
    for (int col = 0; col < 13; ++col) {
      acc[col] = fmaf(b0.x, wreg[col][0],  acc[col]);
      acc[col] = fmaf(b0.y, wreg[col][1],  acc[col]);
      acc[col] = fmaf(b0.z, wreg[col][2],  acc[col]);
      acc[col] = fmaf(b0.w, wreg[col][3],  acc[col]);
      acc[col] = fmaf(b1.x, wreg[col][4],  acc[col]);
      acc[col] = fmaf(b1.y, wreg[col][5],  acc[col]);
      acc[col] = fmaf(b1.z, wreg[col][6],  acc[col]);
      acc[col] = fmaf(b1.w, wreg[col][7],  acc[col]);
      acc[col] = fmaf(b2.x, wreg[col][8],  acc[col]);
      acc[col] = fmaf(b2.y, wreg[col][9],  acc[col]);
      acc[col] = fmaf(b2.z, wreg[col][10], acc[col]);
      acc[col] = fmaf(b2.w, wreg[col][11], acc[col]);
    }

    #pragma unroll
    for (int c = 0; c < 13; ++c) {
      DPP_REDUCE64(acc[c])
    }

    if (l == 63) {
      #pragma unroll
      for (int c = 0; c < 13; ++c)
        featsT[(long)c * 65536 + row0 + r] = acc[c] + bs[c];
    }

    {
      const int pr = (r + 4 < 32) ? (r + 4) : 31;
      const float* xn = xp + pr * 768;
      buf[s][0] = *reinterpret_cast<const float4*>(xn);
      buf[s][1] = *reinterpret_cast<const float4*>(xn + 256);
      buf[s][2] = *reinterpret_cast<const float4*>(xn + 512);
    }
  }
}

// ---------------------------------------------------------------- kernel 2 --
__global__ __launch_bounds__(256) void viterbi_kernel(
    const float* __restrict__ featsT,  // [13][65536]
    const float* __restrict__ trans,   // [13,13]
    float* __restrict__ out)           // [256 + 65536]
{
  __shared__ float fsT[13 * 260];          // feats transposed [to][t] (pad 260)
  __shared__ float lds_ld[256 * 16];       // ld_t[to], t = 0..255
  __shared__ float trL[176];               // trans (169 used)
  __shared__ unsigned char psi[256 * 16];  // psi[t][to]
  __shared__ unsigned char Mm[256];        // [16 chunks][16]
  __shared__ unsigned char bnd[16];
  __shared__ unsigned char path[256];

  const int tid = threadIdx.x;
  const int w = tid >> 6, lane = tid & 63;
  const int b = blockIdx.x;

  #pragma unroll
  for (int i = 0; i < 13; ++i)
    fsT[i * 260 + tid] = featsT[(long)i * 65536 + b * 256 + tid];
  if (tid < 169) trL[tid] = trans[tid];
  __syncthreads();

  // ---- phase 1: serial forward (values only), wave 0, lower half-wave ----
  if (w == 0 && lane < 16) {
    float tr[13];
    #pragma unroll
    for (int f = 0; f < 13; ++f)
      tr[f] = (lane < 13) ? trans[lane * 13 + f] : -1.0e30f;

    const int toc = (lane < 13) ? lane : 0;
    const float* frow = &fsT[toc * 260];

    float ld = (lane == 11) ? 0.0f : NEGV;  // START = 11
    lds_ld[lane] = ld;                      // t = 0 (unguarded, cols 13-15 junk)

    float4 F[4], Fn[4];
    #pragma unroll
    for (int q = 0; q < 4; ++q)
      F[q] = *reinterpret_cast<const float4*>(frow + 4 * q);

    // ---- peeled chunk 0: t = 1..15, branch-free body ----
    {
      #pragma unroll
      for (int q = 0; q < 4; ++q)
        Fn[q] = *reinterpret_cast<const float4*>(frow + 16 + 4 * q);
      #pragma unroll
      for (int k = 1; k < 16; ++k) {
        const float4 fq = F[k >> 2];
        const float ft = ((k & 3) == 0) ? fq.x : ((k & 3) == 1) ? fq.y
                        : ((k & 3) == 2) ? fq.z : fq.w;
        VSTEP(k, ft)
      }
      #pragma unroll
      for (int q = 0; q < 4; ++q) F[q] = Fn[q];
    }

    // ---- chunks 1..15: clean 16-step bodies, no branches ----
    #pragma unroll 1
    for (int g = 1; g < 16; ++g) {
      if (g < 15) {
        #pragma unroll
        for (int q = 0; q < 4; ++q)
          Fn[q] = *reinterpret_cast<const float4*>(frow + (g + 1) * 16 + 4 * q);
      }
      #pragma unroll
      for (int k = 0; k < 16; ++k) {
        const int t = g * 16 + k;
        const float4 fq = F[k >> 2];
        const float ft = ((k & 3) == 0) ? fq.x : ((k & 3) == 1) ? fq.y
                        : ((k & 3) == 2) ? fq.z : fq.w;
        VSTEP(t, ft)
      }
      #pragma unroll
      for (int q = 0; q < 4; ++q) F[q] = Fn[q];
    }
  }
  __syncthreads();

  // ---- phase 2: psi in parallel over t ----
  {
    const int to = tid & 15, dtt = tid >> 4;
    if (to < 13) {
      float trr[13];
      #pragma unroll
      for (int f = 0; f < 13; ++f) trr[f] = trL[to * 13 + f];
      for (int t = (dtt == 0 ? 16 : dtt); t < 256; t += 16) {
        const float* lp = &lds_ld[(t - 1) * 16];
        float4 l0 = *reinterpret_cast<const float4*>(lp);
        float4 l1 = *reinterpret_cast<const float4*>(lp + 4);
        float4 l2 = *reinterpret_cast<const float4*>(lp + 8);
        float4 l3 = *reinterpret_cast<const float4*>(lp + 12);
        float c[13] = {trr[0] + l0.x,  trr[1] + l0.y,  trr[2] + l0.z,
                       trr[3] + l0.w,  trr[4] + l1.x,  trr[5] + l1.y,
                       trr[6] + l1.z,  trr[7] + l1.w,  trr[8] + l2.x,
                       trr[9] + l2.y,  trr[10] + l2.z, trr[11] + l2.w,
                       trr[12] + l3.x};
        float best = c[0]; int bf = 0;
        #pragma unroll
        for (int f = 1; f < 13; ++f) {
          bool gt = c[f] > best;              // strict >: first index wins
          best = gt ? c[f] : best;
          bf   = gt ? f : bf;
        }
        psi[t * 16 + to] = (unsigned char)bf;
      }
    }
  }
  __syncthreads();

  // ---- phase 3: ancestor maps ----
  {
    const int sS = tid & 15, g = tid >> 4;
    if (sS < 13) {
      int cur = sS;
      const int tLo = (g == 0) ? 1 : g * 16;
      for (int t = g * 16 + 15; t >= tLo; --t)
        cur = psi[t * 16 + cur];
      Mm[g * 16 + sS] = (unsigned char)cur;
    }
  }
  __syncthreads();

  // ---- phase 4: softmax output + boundary chase ----
  if (tid == 0) {
    const float* lf = &lds_ld[255 * 16];
    float m = lf[0]; int last = 0;
    #pragma unroll
    for (int i = 1; i < 13; ++i)
      if (lf[i] > m) { m = lf[i]; last = i; }   // strict >: first index
    float ssum = 0.0f;
    #pragma unroll
    for (int i = 0; i < 13; ++i) ssum += expf(lf[i] - m);
    out[b] = 1.0f / (256.0f * ssum);            // max(softmax)/T

    int cur = last;
    bnd[15] = (unsigned char)cur;
    #pragma unroll
    for (int cc = 15; cc >= 1; --cc) {
      cur = Mm[cc * 16 + cur];
      bnd[cc - 1] = (unsigned char)cur;
    }
  }
  __syncthreads();

  // ---- phase 5: interior chases ----
  if (tid < 16) {
    int cur = bnd[tid];
    const int tHi = tid * 16 + 15;
    path[tHi] = (unsigned char)cur;
    const int tLo = (tid == 0) ? 1 : tid * 16;
    for (int t = tHi; t >= tLo; --t) {
      cur = psi[t * 16 + cur];
      path[t - 1] = (unsigned char)cur;
    }
  }
  __syncthreads();

  out[256 + (long)b * 256 + tid] = (float)path[tid];
}

// ------------------------------------------------------------------ launch --
extern "C" void kernel_launch(void* const* d_in, const int* in_sizes, int n_in,
                              void* d_out, int out_size, void* d_ws, size_t ws_size,
                              hipStream_t stream) {
  const float* X     = (const float*)d_in[0];
  const float* W     = (const float*)d_in[1];
  const float* bias  = (const float*)d_in[2];
  const float* trans = (const float*)d_in[3];
  float* out    = (float*)d_out;
  float* featsT = (float*)d_ws;   // 13*65536 floats = 3.4 MB

  feats_kernel<<<512, 256, 0, stream>>>(X, W, bias, featsT);
  viterbi_kernel<<<256, 256, 0, stream>>>(featsT, trans, out);
}

// Round 18
// 77.123 us; speedup vs baseline: 1.5508x; 1.1432x over previous
//
#include <hip/hip_runtime.h>

// BERT-CRF NER, two kernels.
//  K1 feats: byte-identical to round 14 (F ~= 39us).
//  K2 viterbi: r17 structure; the per-step body is now a hand-scheduled
//     inline-asm sequence: 13 readlanes batched through 6 rotating SGPRs
//     (all SGPR reads >=5 instrs after their writes -> no VALU->SGPR hazard
//     stalls), adds grouped, v_max3_f32 tree (exact max), final add.
//     Bit-identical ld values; phases 2-5 byte-identical.
// B=256, T=256, H=768, L=13, START=11.
// Outputs (float32): [0..255] max_p/T; [256..65791] path.

#define NEGV (-10000.0f)

#define DPP_ADD(v, ctrl, rmask)                                               \
  v += __int_as_float(__builtin_amdgcn_update_dpp(                            \
      0, __float_as_int(v), (ctrl), (rmask), 0xF, true));

#define DPP_REDUCE64(v)                                                       \
  DPP_ADD(v, 0x111, 0xF)  /* row_shr:1  */                                    \
  DPP_ADD(v, 0x112, 0xF)  /* row_shr:2  */                                    \
  DPP_ADD(v, 0x114, 0xF)  /* row_shr:4  */                                    \
  DPP_ADD(v, 0x118, 0xF)  /* row_shr:8  */                                    \
  DPP_ADD(v, 0x142, 0xA)  /* row_bcast:15 */                                  \
  DPP_ADD(v, 0x143, 0xC)  /* row_bcast:31 */

// One Viterbi value-step, hand-scheduled. Computes
//   max_f(tr[f] + readlane(ld, f)) + ft        (f = 0..12)
// with readlanes batched 6-wide so no SGPR-read follows its write within
// <5 instructions. v_max3 tree = exact max (order-independent).
__device__ __forceinline__ float vstep_asm(float ld, const float* tr, float ft) {
  float out, v0, v1, v2, v3, v4, v5;
  int s0, s1, s2, s3, s4, s5;
  asm("v_readlane_b32 %[s0], %[ld], 0\n\t"
      "v_readlane_b32 %[s1], %[ld], 1\n\t"
      "v_readlane_b32 %[s2], %[ld], 2\n\t"
      "v_readlane_b32 %[s3], %[ld], 3\n\t"
      "v_readlane_b32 %[s4], %[ld], 4\n\t"
      "v_readlane_b32 %[s5], %[ld], 5\n\t"
      "v_add_f32 %[v0], %[s0], %[t0]\n\t"
      "v_add_f32 %[v1], %[s1], %[t1]\n\t"
      "v_add_f32 %[v2], %[s2], %[t2]\n\t"
      "v_readlane_b32 %[s0], %[ld], 6\n\t"
      "v_readlane_b32 %[s1], %[ld], 7\n\t"
      "v_readlane_b32 %[s2], %[ld], 8\n\t"
      "v_add_f32 %[v3], %[s3], %[t3]\n\t"
      "v_add_f32 %[v4], %[s4], %[t4]\n\t"
      "v_add_f32 %[v5], %[s5], %[t5]\n\t"
      "v_max3_f32 %[v0], %[v0], %[v1], %[v2]\n\t"   // m0
      "v_max3_f32 %[v3], %[v3], %[v4], %[v5]\n\t"   // m1
      "v_readlane_b32 %[s3], %[ld], 9\n\t"
      "v_readlane_b32 %[s4], %[ld], 10\n\t"
      "v_readlane_b32 %[s5], %[ld], 11\n\t"
      "v_add_f32 %[v1], %[s0], %[t6]\n\t"
      "v_add_f32 %[v2], %[s1], %[t7]\n\t"
      "v_add_f32 %[v4], %[s2], %[t8]\n\t"
      "v_readlane_b32 %[s0], %[ld], 12\n\t"
      "v_max3_f32 %[v1], %[v1], %[v2], %[v4]\n\t"   // m2
      "v_add_f32 %[v2], %[s3], %[t9]\n\t"
      "v_add_f32 %[v4], %[s4], %[t10]\n\t"
      "v_add_f32 %[v5], %[s5], %[t11]\n\t"
      "v_max3_f32 %[v2], %[v2], %[v4], %[v5]\n\t"   // m3
      "v_add_f32 %[v4], %[s0], %[t12]\n\t"          // c12
      "v_max3_f32 %[v0], %[v0], %[v3], %[v1]\n\t"   // max(m0,m1,m2)
      "v_max3_f32 %[v0], %[v0], %[v2], %[v4]\n\t"   // max(.., m3, c12)
      "v_add_f32 %[o], %[v0], %[ft]"
      : [o] "=&v"(out),
        [s0] "=&s"(s0), [s1] "=&s"(s1), [s2] "=&s"(s2),
        [s3] "=&s"(s3), [s4] "=&s"(s4), [s5] "=&s"(s5),
        [v0] "=&v"(v0), [v1] "=&v"(v1), [v2] "=&v"(v2),
        [v3] "=&v"(v3), [v4] "=&v"(v4), [v5] "=&v"(v5)
      : [ld] "v"(ld), [ft] "v"(ft),
        [t0] "v"(tr[0]), [t1] "v"(tr[1]), [t2] "v"(tr[2]), [t3] "v"(tr[3]),
        [t4] "v"(tr[4]), [t5] "v"(tr[5]), [t6] "v"(tr[6]), [t7] "v"(tr[7]),
        [t8] "v"(tr[8]), [t9] "v"(tr[9]), [t10] "v"(tr[10]),
        [t11] "v"(tr[11]), [t12] "v"(tr[12]));
  return out;
}

#define VSTEP(t, ftv)                                                         \
  {                                                                           \
    ld = vstep_asm(ld, tr, (ftv));                                            \
    lds_ld[(t) * 16 + lane] = ld;  /* unguarded: cols 13-15 unused junk */    \
  }

// ---------------------------------------------------------------- kernel 1 --
__global__ __launch_bounds__(256)
__attribute__((amdgpu_waves_per_eu(2, 2)))
void feats_kernel(
    const float* __restrict__ X,      // [65536, 768]
    const float* __restrict__ W,      // [13, 768]
    const float* __restrict__ bias,   // [13]
    float* __restrict__ featsT)       // [13][65536]
{
  const int tid = threadIdx.x;
  const int w = tid >> 6, l = tid & 63;
  const long row0 = (long)blockIdx.x * 128 + w * 32;

  float wreg[13][12];
  #pragma unroll
  for (int col = 0; col < 13; ++col) {
    #pragma unroll
    for (int j = 0; j < 3; ++j) {
      float4 v = *reinterpret_cast<const float4*>(W + col * 768 + 256 * j + 4 * l);
      wreg[col][4 * j + 0] = v.x; wreg[col][4 * j + 1] = v.y;
      wreg[col][4 * j + 2] = v.z; wreg[col][4 * j + 3] = v.w;
    }
  }
  float bs[13];
  #pragma unroll
  for (int c = 0; c < 13; ++c) bs[c] = bias[c];

  const float* xp = X + row0 * 768 + 4 * l;

  float4 buf[4][3];
  #pragma unroll
  for (int i = 0; i < 4; ++i) {
    buf[i][0] = *reinterpret_cast<const float4*>(xp + i * 768);
    buf[i][1] = *reinterpret_cast<const float4*>(xp + i * 768 + 256);
    buf[i][2] = *reinterpret_cast<const float4*>(xp + i * 768 + 512);
  }

  #pragma unroll 4
  for (int r = 0; r < 32; ++r) {
    const int s = r & 3;
    const float4 b0 = buf[s][0], b1 = buf[s][1], b2 = buf[s][2];

    float acc[13];
    #pragma unroll
    for (int c = 0; c < 13; ++c) acc[c] = 0.0f;
    #pragma unroll
    for (int col = 0; col < 13; ++col) {
      acc[col] = fmaf(b0.x, wreg[col][0],  acc[col]);
      acc[col] = fmaf(b0.y, wreg[col][1],  acc[col]);
      acc[col] = fmaf(b0.z, wreg[col][2],  acc[col]);
      acc[col] = fmaf(b0.w, wreg[col][3],  acc[col]);
      acc[col] = fmaf(b1.x, wreg[col][4],  acc[col]);
      acc[col] = fmaf(b1.y, wreg[col][5],  acc[col]);
      acc[col] = fmaf(b1.z, wreg[col][6],  acc[col]);
      acc[col] = fmaf(b1.w, wreg[col][7],  acc[col]);
      acc[col] = fmaf(b2.x, wreg[col][8],  acc[col]);
      acc[col] = fmaf(b2.y, wreg[col][9],  acc[col]);
      acc[col] = fmaf(b2.z, wreg[col][10], acc[col]);
      acc[col] = fmaf(b2.w, wreg[col][11], acc[col]);
    }

    #pragma unroll
    for (int c = 0; c < 13; ++c) {
      DPP_REDUCE64(acc[c])
    }

    if (l == 63) {
      #pragma unroll
      for (int c = 0; c < 13; ++c)
        featsT[(long)c * 65536 + row0 + r] = acc[c] + bs[c];
    }

    {
      const int pr = (r + 4 < 32) ? (r + 4) : 31;
      const float* xn = xp + pr * 768;
      buf[s][0] = *reinterpret_cast<const float4*>(xn);
      buf[s][1] = *reinterpret_cast<const float4*>(xn + 256);
      buf[s][2] = *reinterpret_cast<const float4*>(xn + 512);
    }
  }
}

// ---------------------------------------------------------------- kernel 2 --
__global__ __launch_bounds__(256) void viterbi_kernel(
    const float* __restrict__ featsT,  // [13][65536]
    const float* __restrict__ trans,   // [13,13]
    float* __restrict__ out)           // [256 + 65536]
{
  __shared__ float fsT[13 * 260];          // feats transposed [to][t] (pad 260)
  __shared__ float lds_ld[256 * 16];       // ld_t[to], t = 0..255
  __shared__ float trL[176];               // trans (169 used)
  __shared__ unsigned char psi[256 * 16];  // psi[t][to]
  __shared__ unsigned char Mm[256];        // [16 chunks][16]
  __shared__ unsigned char bnd[16];
  __shared__ unsigned char path[256];

  const int tid = threadIdx.x;
  const int w = tid >> 6, lane = tid & 63;
  const int b = blockIdx.x;

  #pragma unroll
  for (int i = 0; i < 13; ++i)
    fsT[i * 260 + tid] = featsT[(long)i * 65536 + b * 256 + tid];
  if (tid < 169) trL[tid] = trans[tid];
  __syncthreads();

  // ---- phase 1: serial forward (values only), wave 0, lower half-wave ----
  if (w == 0 && lane < 16) {
    float tr[13];
    #pragma unroll
    for (int f = 0; f < 13; ++f)
      tr[f] = (lane < 13) ? trans[lane * 13 + f] : -1.0e30f;

    const int toc = (lane < 13) ? lane : 0;
    const float* frow = &fsT[toc * 260];

    float ld = (lane == 11) ? 0.0f : NEGV;  // START = 11
    lds_ld[lane] = ld;                      // t = 0 (unguarded)

    float4 F[4], Fn[4];
    #pragma unroll
    for (int q = 0; q < 4; ++q)
      F[q] = *reinterpret_cast<const float4*>(frow + 4 * q);

    // ---- peeled chunk 0: t = 1..15, branch-free body ----
    {
      #pragma unroll
      for (int q = 0; q < 4; ++q)
        Fn[q] = *reinterpret_cast<const float4*>(frow + 16 + 4 * q);
      #pragma unroll
      for (int k = 1; k < 16; ++k) {
        const float4 fq = F[k >> 2];
        const float ftv = ((k & 3) == 0) ? fq.x : ((k & 3) == 1) ? fq.y
                         : ((k & 3) == 2) ? fq.z : fq.w;
        VSTEP(k, ftv)
      }
      #pragma unroll
      for (int q = 0; q < 4; ++q) F[q] = Fn[q];
    }

    // ---- chunks 1..15: clean 16-step bodies ----
    #pragma unroll 1
    for (int g = 1; g < 16; ++g) {
      if (g < 15) {
        #pragma unroll
        for (int q = 0; q < 4; ++q)
          Fn[q] = *reinterpret_cast<const float4*>(frow + (g + 1) * 16 + 4 * q);
      }
      #pragma unroll
      for (int k = 0; k < 16; ++k) {
        const int t = g * 16 + k;
        const float4 fq = F[k >> 2];
        const float ftv = ((k & 3) == 0) ? fq.x : ((k & 3) == 1) ? fq.y
                         : ((k & 3) == 2) ? fq.z : fq.w;
        VSTEP(t, ftv)
      }
      #pragma unroll
      for (int q = 0; q < 4; ++q) F[q] = Fn[q];
    }
  }
  __syncthreads();

  // ---- phase 2: psi in parallel over t ----
  {
    const int to = tid & 15, dtt = tid >> 4;
    if (to < 13) {
      float trr[13];
      #pragma unroll
      for (int f = 0; f < 13; ++f) trr[f] = trL[to * 13 + f];
      for (int t = (dtt == 0 ? 16 : dtt); t < 256; t += 16) {
        const float* lp = &lds_ld[(t - 1) * 16];
        float4 l0 = *reinterpret_cast<const float4*>(lp);
        float4 l1 = *reinterpret_cast<const float4*>(lp + 4);
        float4 l2 = *reinterpret_cast<const float4*>(lp + 8);
        float4 l3 = *reinterpret_cast<const float4*>(lp + 12);
        float c[13] = {trr[0] + l0.x,  trr[1] + l0.y,  trr[2] + l0.z,
                       trr[3] + l0.w,  trr[4] + l1.x,  trr[5] + l1.y,
                       trr[6] + l1.z,  trr[7] + l1.w,  trr[8] + l2.x,
                       trr[9] + l2.y,  trr[10] + l2.z, trr[11] + l2.w,
                       trr[12] + l3.x};
        float best = c[0]; int bf = 0;
        #pragma unroll
        for (int f = 1; f < 13; ++f) {
          bool gt = c[f] > best;              // strict >: first index wins
          best = gt ? c[f] : best;
          bf   = gt ? f : bf;
        }
        psi[t * 16 + to] = (unsigned char)bf;
      }
    }
  }
  __syncthreads();

  // ---- phase 3: ancestor maps ----
  {
    const int sS = tid & 15, g = tid >> 4;
    if (sS < 13) {
      int cur = sS;
      const int tLo = (g == 0) ? 1 : g * 16;
      for (int t = g * 16 + 15; t >= tLo; --t)
        cur = psi[t * 16 + cur];
      Mm[g * 16 + sS] = (unsigned char)cur;
    }
  }
  __syncthreads();

  // ---- phase 4: softmax output + boundary chase ----
  if (tid == 0) {
    const float* lf = &lds_ld[255 * 16];
    float m = lf[0]; int last = 0;
    #pragma unroll
    for (int i = 1; i < 13; ++i)
      if (lf[i] > m) { m = lf[i]; last = i; }   // strict >: first index
    float ssum = 0.0f;
    #pragma unroll
    for (int i = 0; i < 13; ++i) ssum += expf(lf[i] - m);
    out[b] = 1.0f / (256.0f * ssum);            // max(softmax)/T

    int cur = last;
    bnd[15] = (unsigned char)cur;
    #pragma unroll
    for (int cc = 15; cc >= 1; --cc) {
      cur = Mm[cc * 16 + cur];
      bnd[cc - 1] = (unsigned char)cur;
    }
  }
  __syncthreads();

  // ---- phase 5: interior chases ----
  if (tid < 16) {
    int cur = bnd[tid];
    const int tHi = tid * 16 + 15;
    path[tHi] = (unsigned char)cur;
    const int tLo = (tid == 0) ? 1 : tid * 16;
    for (int t = tHi; t >= tLo; --t) {
      cur = psi[t * 16 + cur];
      path[t - 1] = (unsigned char)cur;
    }
  }
  __syncthreads();

  out[256 + (long)b * 256 + tid] = (float)path[tid];
}

// ------------------------------------------------------------------ launch --
extern "C" void kernel_launch(void* const* d_in, const int* in_sizes, int n_in,
                              void* d_out, int out_size, void* d_ws, size_t ws_size,
                              hipStream_t stream) {
  const float* X     = (const float*)d_in[0];
  const float* W     = (const float*)d_in[1];
  const float* bias  = (const float*)d_in[2];
  const float* trans = (const float*)d_in[3];
  float* out    = (float*)d_out;
  float* featsT = (float*)d_ws;   // 13*65536 floats = 3.4 MB

  feats_kernel<<<512, 256, 0, stream>>>(X, W, bias, featsT);
  viterbi_kernel<<<256, 256, 0, stream>>>(featsT, trans, out);
}

// Round 19
// 69.790 us; speedup vs baseline: 1.7137x; 1.1051x over previous
//
#include <hip/hip_runtime.h>

// Fused BERT-CRF NER: ONE kernel, grid 256 (block=batch), 512 threads (8 waves).
//  Feats part: r14/r18 structure verbatim (W in VGPRs, 4-deep ring, DPP
//    reduce, lane-63 epilogue) — 8 waves x 32 rows = 256 rows = this batch;
//    results written DIRECTLY to LDS fsT[13][260] (no global featsT, no
//    second launch, no re-staging).
//  Viterbi part: r18 verbatim — asm phase 1 (wave 0), psi recompute,
//    ancestor maps, boundary+interior backtrace, softmax. Phase-2 indexing
//    adapted 256->512 threads (stride 32); phases 3/5 guarded to tid<256.
// B=256, T=256, H=768, L=13, START=11.
// Outputs (float32): [0..255] max_p/T; [256..65791] path.

#define NEGV (-10000.0f)

#define DPP_ADD(v, ctrl, rmask)                                               \
  v += __int_as_float(__builtin_amdgcn_update_dpp(                            \
      0, __float_as_int(v), (ctrl), (rmask), 0xF, true));

#define DPP_REDUCE64(v)                                                       \
  DPP_ADD(v, 0x111, 0xF)  /* row_shr:1  */                                    \
  DPP_ADD(v, 0x112, 0xF)  /* row_shr:2  */                                    \
  DPP_ADD(v, 0x114, 0xF)  /* row_shr:4  */                                    \
  DPP_ADD(v, 0x118, 0xF)  /* row_shr:8  */                                    \
  DPP_ADD(v, 0x142, 0xA)  /* row_bcast:15 */                                  \
  DPP_ADD(v, 0x143, 0xC)  /* row_bcast:31 */

// One Viterbi value-step, hand-scheduled (r18, proven -11us): readlanes
// batched 6-wide through rotating SGPRs (no SGPR-read within 5 instrs of its
// write), v_max3 tree (exact), final add. Bit-identical ld.
__device__ __forceinline__ float vstep_asm(float ld, const float* tr, float ft) {
  float out, v0, v1, v2, v3, v4, v5;
  int s0, s1, s2, s3, s4, s5;
  asm("v_readlane_b32 %[s0], %[ld], 0\n\t"
      "v_readlane_b32 %[s1], %[ld], 1\n\t"
      "v_readlane_b32 %[s2], %[ld], 2\n\t"
      "v_readlane_b32 %[s3], %[ld], 3\n\t"
      "v_readlane_b32 %[s4], %[ld], 4\n\t"
      "v_readlane_b32 %[s5], %[ld], 5\n\t"
      "v_add_f32 %[v0], %[s0], %[t0]\n\t"
      "v_add_f32 %[v1], %[s1], %[t1]\n\t"
      "v_add_f32 %[v2], %[s2], %[t2]\n\t"
      "v_readlane_b32 %[s0], %[ld], 6\n\t"
      "v_readlane_b32 %[s1], %[ld], 7\n\t"
      "v_readlane_b32 %[s2], %[ld], 8\n\t"
      "v_add_f32 %[v3], %[s3], %[t3]\n\t"
      "v_add_f32 %[v4], %[s4], %[t4]\n\t"
      "v_add_f32 %[v5], %[s5], %[t5]\n\t"
      "v_max3_f32 %[v0], %[v0], %[v1], %[v2]\n\t"   // m0
      "v_max3_f32 %[v3], %[v3], %[v4], %[v5]\n\t"   // m1
      "v_readlane_b32 %[s3], %[ld], 9\n\t"
      "v_readlane_b32 %[s4], %[ld], 10\n\t"
      "v_readlane_b32 %[s5], %[ld], 11\n\t"
      "v_add_f32 %[v1], %[s0], %[t6]\n\t"
      "v_add_f32 %[v2], %[s1], %[t7]\n\t"
      "v_add_f32 %[v4], %[s2], %[t8]\n\t"
      "v_readlane_b32 %[s0], %[ld], 12\n\t"
      "v_max3_f32 %[v1], %[v1], %[v2], %[v4]\n\t"   // m2
      "v_add_f32 %[v2], %[s3], %[t9]\n\t"
      "v_add_f32 %[v4], %[s4], %[t10]\n\t"
      "v_add_f32 %[v5], %[s5], %[t11]\n\t"
      "v_max3_f32 %[v2], %[v2], %[v4], %[v5]\n\t"   // m3
      "v_add_f32 %[v4], %[s0], %[t12]\n\t"          // c12
      "v_max3_f32 %[v0], %[v0], %[v3], %[v1]\n\t"   // max(m0,m1,m2)
      "v_max3_f32 %[v0], %[v0], %[v2], %[v4]\n\t"   // max(.., m3, c12)
      "v_add_f32 %[o], %[v0], %[ft]"
      : [o] "=&v"(out),
        [s0] "=&s"(s0), [s1] "=&s"(s1), [s2] "=&s"(s2),
        [s3] "=&s"(s3), [s4] "=&s"(s4), [s5] "=&s"(s5),
        [v0] "=&v"(v0), [v1] "=&v"(v1), [v2] "=&v"(v2),
        [v3] "=&v"(v3), [v4] "=&v"(v4), [v5] "=&v"(v5)
      : [ld] "v"(ld), [ft] "v"(ft),
        [t0] "v"(tr[0]), [t1] "v"(tr[1]), [t2] "v"(tr[2]), [t3] "v"(tr[3]),
        [t4] "v"(tr[4]), [t5] "v"(tr[5]), [t6] "v"(tr[6]), [t7] "v"(tr[7]),
        [t8] "v"(tr[8]), [t9] "v"(tr[9]), [t10] "v"(tr[10]),
        [t11] "v"(tr[11]), [t12] "v"(tr[12]));
  return out;
}

#define VSTEP(t, ftv)                                                         \
  {                                                                           \
    ld = vstep_asm(ld, tr, (ftv));                                            \
    lds_ld[(t) * 16 + lane] = ld;  /* unguarded: cols 13-15 unused junk */    \
  }

__global__ __launch_bounds__(512)
__attribute__((amdgpu_waves_per_eu(2, 2)))
void fused_kernel(
    const float* __restrict__ X,      // [65536, 768]
    const float* __restrict__ W,      // [13, 768]
    const float* __restrict__ bias,   // [13]
    const float* __restrict__ trans,  // [13,13]
    float* __restrict__ out)          // [256 + 65536]
{
  __shared__ float fsT[13 * 260];          // feats transposed [to][t] (pad 260)
  __shared__ float lds_ld[256 * 16];       // ld_t[to], t = 0..255
  __shared__ float trL[176];               // trans (169 used)
  __shared__ unsigned char psi[256 * 16];  // psi[t][to]
  __shared__ unsigned char Mm[256];        // [16 chunks][16]
  __shared__ unsigned char bnd[16];
  __shared__ unsigned char path[256];

  const int tid = threadIdx.x;
  const int w = tid >> 6, l = tid & 63;
  const int b = blockIdx.x;

  if (tid < 169) trL[tid] = trans[tid];

  // ================= feats: 8 waves x 32 rows = this batch ==================
  {
    float wreg[13][12];
    #pragma unroll
    for (int col = 0; col < 13; ++col) {
      #pragma unroll
      for (int j = 0; j < 3; ++j) {
        float4 v = *reinterpret_cast<const float4*>(W + col * 768 + 256 * j + 4 * l);
        wreg[col][4 * j + 0] = v.x; wreg[col][4 * j + 1] = v.y;
        wreg[col][4 * j + 2] = v.z; wreg[col][4 * j + 3] = v.w;
      }
    }
    float bs[13];
    #pragma unroll
    for (int c = 0; c < 13; ++c) bs[c] = bias[c];

    // this wave's 32 rows: global rows b*256 + w*32 + r, local t = w*32 + r
    const float* xp = X + ((long)b * 256 + w * 32) * 768 + 4 * l;

    float4 buf[4][3];
    #pragma unroll
    for (int i = 0; i < 4; ++i) {
      buf[i][0] = *reinterpret_cast<const float4*>(xp + i * 768);
      buf[i][1] = *reinterpret_cast<const float4*>(xp + i * 768 + 256);
      buf[i][2] = *reinterpret_cast<const float4*>(xp + i * 768 + 512);
    }

    #pragma unroll 4
    for (int r = 0; r < 32; ++r) {
      const int s = r & 3;
      const float4 b0 = buf[s][0], b1 = buf[s][1], b2 = buf[s][2];

      float acc[13];
      #pragma unroll
      for (int c = 0; c < 13; ++c) acc[c] = 0.0f;
      #pragma unroll
      for (int col = 0; col < 13; ++col) {
        acc[col] = fmaf(b0.x, wreg[col][0],  acc[col]);
        acc[col] = fmaf(b0.y, wreg[col][1],  acc[col]);
        acc[col] = fmaf(b0.z, wreg[col][2],  acc[col]);
        acc[col] = fmaf(b0.w, wreg[col][3],  acc[col]);
        acc[col] = fmaf(b1.x, wreg[col][4],  acc[col]);
        acc[col] = fmaf(b1.y, wreg[col][5],  acc[col]);
        acc[col] = fmaf(b1.z, wreg[col][6],  acc[col]);
        acc[col] = fmaf(b1.w, wreg[col][7],  acc[col]);
        acc[col] = fmaf(b2.x, wreg[col][8],  acc[col]);
        acc[col] = fmaf(b2.y, wreg[col][9],  acc[col]);
        acc[col] = fmaf(b2.z, wreg[col][10], acc[col]);
        acc[col] = fmaf(b2.w, wreg[col][11], acc[col]);
      }

      #pragma unroll
      for (int c = 0; c < 13; ++c) {
        DPP_REDUCE64(acc[c])
      }

      if (l == 63) {            // totals live in lane 63: write straight to LDS
        const int t = w * 32 + r;
        #pragma unroll
        for (int c = 0; c < 13; ++c)
          fsT[c * 260 + t] = acc[c] + bs[c];
      }

      {
        const int pr = (r + 4 < 32) ? (r + 4) : 31;
        const float* xn = xp + pr * 768;
        buf[s][0] = *reinterpret_cast<const float4*>(xn);
        buf[s][1] = *reinterpret_cast<const float4*>(xn + 256);
        buf[s][2] = *reinterpret_cast<const float4*>(xn + 512);
      }
    }
  }
  __syncthreads();

  // ================= viterbi (r18 verbatim, 512-thread indexing) ============
  const int lane = l;

  // ---- phase 1: serial forward (values only), wave 0, lower half-wave ----
  if (w == 0 && lane < 16) {
    float tr[13];
    #pragma unroll
    for (int f = 0; f < 13; ++f)
      tr[f] = (lane < 13) ? trans[lane * 13 + f] : -1.0e30f;

    const int toc = (lane < 13) ? lane : 0;
    const float* frow = &fsT[toc * 260];

    float ld = (lane == 11) ? 0.0f : NEGV;  // START = 11
    lds_ld[lane] = ld;                      // t = 0 (unguarded)

    float4 F[4], Fn[4];
    #pragma unroll
    for (int q = 0; q < 4; ++q)
      F[q] = *reinterpret_cast<const float4*>(frow + 4 * q);

    {  // peeled chunk 0: t = 1..15
      #pragma unroll
      for (int q = 0; q < 4; ++q)
        Fn[q] = *reinterpret_cast<const float4*>(frow + 16 + 4 * q);
      #pragma unroll
      for (int k = 1; k < 16; ++k) {
        const float4 fq = F[k >> 2];
        const float ftv = ((k & 3) == 0) ? fq.x : ((k & 3) == 1) ? fq.y
                         : ((k & 3) == 2) ? fq.z : fq.w;
        VSTEP(k, ftv)
      }
      #pragma unroll
      for (int q = 0; q < 4; ++q) F[q] = Fn[q];
    }

    #pragma unroll 1
    for (int g = 1; g < 16; ++g) {
      if (g < 15) {
        #pragma unroll
        for (int q = 0; q < 4; ++q)
          Fn[q] = *reinterpret_cast<const float4*>(frow + (g + 1) * 16 + 4 * q);
      }
      #pragma unroll
      for (int k = 0; k < 16; ++k) {
        const int t = g * 16 + k;
        const float4 fq = F[k >> 2];
        const float ftv = ((k & 3) == 0) ? fq.x : ((k & 3) == 1) ? fq.y
                         : ((k & 3) == 2) ? fq.z : fq.w;
        VSTEP(t, ftv)
      }
      #pragma unroll
      for (int q = 0; q < 4; ++q) F[q] = Fn[q];
    }
  }
  __syncthreads();

  // ---- phase 2: psi in parallel over t (512 threads -> stride 32) ----
  {
    const int to = tid & 15, dtt = tid >> 4;   // dtt = 0..31
    if (to < 13) {
      float trr[13];
      #pragma unroll
      for (int f = 0; f < 13; ++f) trr[f] = trL[to * 13 + f];
      for (int t = (dtt == 0 ? 32 : dtt); t < 256; t += 32) {
        const float* lp = &lds_ld[(t - 1) * 16];
        float4 l0 = *reinterpret_cast<const float4*>(lp);
        float4 l1 = *reinterpret_cast<const float4*>(lp + 4);
        float4 l2 = *reinterpret_cast<const float4*>(lp + 8);
        float4 l3 = *reinterpret_cast<const float4*>(lp + 12);
        float c[13] = {trr[0] + l0.x,  trr[1] + l0.y,  trr[2] + l0.z,
                       trr[3] + l0.w,  trr[4] + l1.x,  trr[5] + l1.y,
                       trr[6] + l1.z,  trr[7] + l1.w,  trr[8] + l2.x,
                       trr[9] + l2.y,  trr[10] + l2.z, trr[11] + l2.w,
                       trr[12] + l3.x};
        float best = c[0]; int bf = 0;
        #pragma unroll
        for (int f = 1; f < 13; ++f) {
          bool gt = c[f] > best;              // strict >: first index wins
          best = gt ? c[f] : best;
          bf   = gt ? f : bf;
        }
        psi[t * 16 + to] = (unsigned char)bf;
      }
    }
  }
  __syncthreads();

  // ---- phase 3: ancestor maps (tid < 256 only) ----
  if (tid < 256) {
    const int sS = tid & 15, g = tid >> 4;     // g = 0..15
    if (sS < 13) {
      int cur = sS;
      const int tLo = (g == 0) ? 1 : g * 16;
      for (int t = g * 16 + 15; t >= tLo; --t)
        cur = psi[t * 16 + cur];
      Mm[g * 16 + sS] = (unsigned char)cur;
    }
  }
  __syncthreads();

  // ---- phase 4: softmax output + boundary chase ----
  if (tid == 0) {
    const float* lf = &lds_ld[255 * 16];
    float m = lf[0]; int last = 0;
    #pragma unroll
    for (int i = 1; i < 13; ++i)
      if (lf[i] > m) { m = lf[i]; last = i; }   // strict >: first index
    float ssum = 0.0f;
    #pragma unroll
    for (int i = 0; i < 13; ++i) ssum += expf(lf[i] - m);
    out[b] = 1.0f / (256.0f * ssum);            // max(softmax)/T

    int cur = last;
    bnd[15] = (unsigned char)cur;
    #pragma unroll
    for (int cc = 15; cc >= 1; --cc) {
      cur = Mm[cc * 16 + cur];
      bnd[cc - 1] = (unsigned char)cur;
    }
  }
  __syncthreads();

  // ---- phase 5: interior chases ----
  if (tid < 16) {
    int cur = bnd[tid];
    const int tHi = tid * 16 + 15;
    path[tHi] = (unsigned char)cur;
    const int tLo = (tid == 0) ? 1 : tid * 16;
    for (int t = tHi; t >= tLo; --t) {
      cur = psi[t * 16 + cur];
      path[t - 1] = (unsigned char)cur;
    }
  }
  __syncthreads();

  if (tid < 256)
    out[256 + (long)b * 256 + tid] = (float)path[tid];
}

// ------------------------------------------------------------------ launch --
extern "C" void kernel_launch(void* const* d_in, const int* in_sizes, int n_in,
                              void* d_out, int out_size, void* d_ws, size_t ws_size,
                              hipStream_t stream) {
  const float* X     = (const float*)d_in[0];
  const float* W     = (const float*)d_in[1];
  const float* bias  = (const float*)d_in[2];
  const float* trans = (const float*)d_in[3];
  float* out = (float*)d_out;

  fused_kernel<<<256, 512, 0, stream>>>(X, W, bias, trans, out);
}

// Round 20
// 54.656 us; speedup vs baseline: 2.1882x; 1.2769x over previous
//
#include <hip/hip_runtime.h>

// Fused BERT-CRF NER with PRODUCER/CONSUMER overlap. One kernel, grid 256
// (block=batch), 512 threads (8 waves).
//  Waves 1..7 (producers): feats rows round-robin (row = (w-1) + 7i), r14
//    math verbatim (W in VGPRs, 4-deep ring, DPP reduce); lane 63 writes the
//    13 fsT values, drains lgkmcnt, then sets flags[row].
//  Wave 0 (consumer): r18 asm Viterbi chain; per 16-step chunk, 16 lanes
//    spin on flags[g*16+lane] (__all gate) then run 16 VSTEPs.
//  After one barrier: phases 2-5 (psi recompute, ancestor maps, backtrace,
//    softmax) verbatim from r19. Bit-identical math throughout.
// B=256, T=256, H=768, L=13, START=11.
// Outputs (float32): [0..255] max_p/T; [256..65791] path.

#define NEGV (-10000.0f)

#define DPP_ADD(v, ctrl, rmask)                                               \
  v += __int_as_float(__builtin_amdgcn_update_dpp(                            \
      0, __float_as_int(v), (ctrl), (rmask), 0xF, true));

#define DPP_REDUCE64(v)                                                       \
  DPP_ADD(v, 0x111, 0xF)  /* row_shr:1  */                                    \
  DPP_ADD(v, 0x112, 0xF)  /* row_shr:2  */                                    \
  DPP_ADD(v, 0x114, 0xF)  /* row_shr:4  */                                    \
  DPP_ADD(v, 0x118, 0xF)  /* row_shr:8  */                                    \
  DPP_ADD(v, 0x142, 0xA)  /* row_bcast:15 */                                  \
  DPP_ADD(v, 0x143, 0xC)  /* row_bcast:31 */

// One Viterbi value-step, hand-scheduled (r18, proven): readlanes batched
// 6-wide through rotating SGPRs, v_max3 tree (exact), final add.
__device__ __forceinline__ float vstep_asm(float ld, const float* tr, float ft) {
  float out, v0, v1, v2, v3, v4, v5;
  int s0, s1, s2, s3, s4, s5;
  asm("v_readlane_b32 %[s0], %[ld], 0\n\t"
      "v_readlane_b32 %[s1], %[ld], 1\n\t"
      "v_readlane_b32 %[s2], %[ld], 2\n\t"
      "v_readlane_b32 %[s3], %[ld], 3\n\t"
      "v_readlane_b32 %[s4], %[ld], 4\n\t"
      "v_readlane_b32 %[s5], %[ld], 5\n\t"
      "v_add_f32 %[v0], %[s0], %[t0]\n\t"
      "v_add_f32 %[v1], %[s1], %[t1]\n\t"
      "v_add_f32 %[v2], %[s2], %[t2]\n\t"
      "v_readlane_b32 %[s0], %[ld], 6\n\t"
      "v_readlane_b32 %[s1], %[ld], 7\n\t"
      "v_readlane_b32 %[s2], %[ld], 8\n\t"
      "v_add_f32 %[v3], %[s3], %[t3]\n\t"
      "v_add_f32 %[v4], %[s4], %[t4]\n\t"
      "v_add_f32 %[v5], %[s5], %[t5]\n\t"
      "v_max3_f32 %[v0], %[v0], %[v1], %[v2]\n\t"   // m0
      "v_max3_f32 %[v3], %[v3], %[v4], %[v5]\n\t"   // m1
      "v_readlane_b32 %[s3], %[ld], 9\n\t"
      "v_readlane_b32 %[s4], %[ld], 10\n\t"
      "v_readlane_b32 %[s5], %[ld], 11\n\t"
      "v_add_f32 %[v1], %[s0], %[t6]\n\t"
      "v_add_f32 %[v2], %[s1], %[t7]\n\t"
      "v_add_f32 %[v4], %[s2], %[t8]\n\t"
      "v_readlane_b32 %[s0], %[ld], 12\n\t"
      "v_max3_f32 %[v1], %[v1], %[v2], %[v4]\n\t"   // m2
      "v_add_f32 %[v2], %[s3], %[t9]\n\t"
      "v_add_f32 %[v4], %[s4], %[t10]\n\t"
      "v_add_f32 %[v5], %[s5], %[t11]\n\t"
      "v_max3_f32 %[v2], %[v2], %[v4], %[v5]\n\t"   // m3
      "v_add_f32 %[v4], %[s0], %[t12]\n\t"          // c12
      "v_max3_f32 %[v0], %[v0], %[v3], %[v1]\n\t"   // max(m0,m1,m2)
      "v_max3_f32 %[v0], %[v0], %[v2], %[v4]\n\t"   // max(.., m3, c12)
      "v_add_f32 %[o], %[v0], %[ft]"
      : [o] "=&v"(out),
        [s0] "=&s"(s0), [s1] "=&s"(s1), [s2] "=&s"(s2),
        [s3] "=&s"(s3), [s4] "=&s"(s4), [s5] "=&s"(s5),
        [v0] "=&v"(v0), [v1] "=&v"(v1), [v2] "=&v"(v2),
        [v3] "=&v"(v3), [v4] "=&v"(v4), [v5] "=&v"(v5)
      : [ld] "v"(ld), [ft] "v"(ft),
        [t0] "v"(tr[0]), [t1] "v"(tr[1]), [t2] "v"(tr[2]), [t3] "v"(tr[3]),
        [t4] "v"(tr[4]), [t5] "v"(tr[5]), [t6] "v"(tr[6]), [t7] "v"(tr[7]),
        [t8] "v"(tr[8]), [t9] "v"(tr[9]), [t10] "v"(tr[10]),
        [t11] "v"(tr[11]), [t12] "v"(tr[12]));
  return out;
}

__global__ __launch_bounds__(512)
__attribute__((amdgpu_waves_per_eu(2, 2)))
void fused_kernel(
    const float* __restrict__ X,      // [65536, 768]
    const float* __restrict__ W,      // [13, 768]
    const float* __restrict__ bias,   // [13]
    const float* __restrict__ trans,  // [13,13]
    float* __restrict__ out)          // [256 + 65536]
{
  __shared__ float fsT[13 * 260];          // feats transposed [to][t]
  __shared__ float lds_ld[256 * 16];       // ld_t[to]
  __shared__ float trL[176];               // trans (169 used)
  __shared__ unsigned char psi[256 * 16];  // psi[t][to]
  __shared__ unsigned char Mm[256];
  __shared__ unsigned char bnd[16];
  __shared__ unsigned char path[256];
  __shared__ int flags[256];               // per-row ready flags

  const int tid = threadIdx.x;
  const int w = tid >> 6, l = tid & 63;
  const int b = blockIdx.x;

  if (tid < 169) trL[tid] = trans[tid];
  if (tid < 256) flags[tid] = 0;
  __syncthreads();

  if (w == 0) {
    // ================== CONSUMER: Viterbi chain (lanes 0-15) ================
    if (l < 16) {
      const int lane = l;
      float tr[13];
      #pragma unroll
      for (int f = 0; f < 13; ++f)
        tr[f] = (lane < 13) ? trans[lane * 13 + f] : -1.0e30f;

      const int toc = (lane < 13) ? lane : 0;
      const float* frow = &fsT[toc * 260];
      volatile int* vf = flags;

      float ld = (lane == 11) ? 0.0f : NEGV;  // START = 11
      lds_ld[lane] = ld;                      // t = 0

      #pragma unroll 1
      for (int g = 0; g < 16; ++g) {
        // wait until all 16 rows of this chunk are produced
        while (!__all(vf[g * 16 + lane] != 0)) {}
        asm volatile("" ::: "memory");       // fence: loads below stay below

        float4 F[4];
        #pragma unroll
        for (int q = 0; q < 4; ++q)
          F[q] = *reinterpret_cast<const float4*>(frow + g * 16 + 4 * q);

        if (g == 0) {
          #pragma unroll
          for (int k = 1; k < 16; ++k) {
            const float4 fq = F[k >> 2];
            const float ftv = ((k & 3) == 0) ? fq.x : ((k & 3) == 1) ? fq.y
                             : ((k & 3) == 2) ? fq.z : fq.w;
            ld = vstep_asm(ld, tr, ftv);
            lds_ld[k * 16 + lane] = ld;
          }
        } else {
          #pragma unroll
          for (int k = 0; k < 16; ++k) {
            const int t = g * 16 + k;
            const float4 fq = F[k >> 2];
            const float ftv = ((k & 3) == 0) ? fq.x : ((k & 3) == 1) ? fq.y
                             : ((k & 3) == 2) ? fq.z : fq.w;
            ld = vstep_asm(ld, tr, ftv);
            lds_ld[t * 16 + lane] = ld;
          }
        }
      }
    }
  } else {
    // ==================== PRODUCERS: feats rows (waves 1-7) =================
    const int pw = w - 1;                    // 0..6
    float wreg[13][12];
    #pragma unroll
    for (int col = 0; col < 13; ++col) {
      #pragma unroll
      for (int j = 0; j < 3; ++j) {
        float4 v = *reinterpret_cast<const float4*>(W + col * 768 + 256 * j + 4 * l);
        wreg[col][4 * j + 0] = v.x; wreg[col][4 * j + 1] = v.y;
        wreg[col][4 * j + 2] = v.z; wreg[col][4 * j + 3] = v.w;
      }
    }
    float bs[13];
    #pragma unroll
    for (int c = 0; c < 13; ++c) bs[c] = bias[c];

    const float* Xb = X + (long)b * 196608 + 4 * l;

    // 4-deep ring: rows pw, pw+7, pw+14, pw+21
    float4 buf[4][3];
    #pragma unroll
    for (int i = 0; i < 4; ++i) {
      const float* xr = Xb + (pw + 7 * i) * 768;
      buf[i][0] = *reinterpret_cast<const float4*>(xr);
      buf[i][1] = *reinterpret_cast<const float4*>(xr + 256);
      buf[i][2] = *reinterpret_cast<const float4*>(xr + 512);
    }

    #define PROW(i, s)                                                        \
    {                                                                         \
      const int r = pw + 7 * (i);                                             \
      const float4 b0 = buf[s][0], b1 = buf[s][1], b2 = buf[s][2];            \
      float acc[13];                                                          \
      _Pragma("unroll")                                                       \
      for (int c = 0; c < 13; ++c) acc[c] = 0.0f;                             \
      _Pragma("unroll")                                                       \
      for (int col = 0; col < 13; ++col) {                                    \
        acc[col] = fmaf(b0.x, wreg[col][0],  acc[col]);                       \
        acc[col] = fmaf(b0.y, wreg[col][1],  acc[col]);                       \
        acc[col] = fmaf(b0.z, wreg[col][2],  acc[col]);                       \
        acc[col] = fmaf(b0.w, wreg[col][3],  acc[col]);                       \
        acc[col] = fmaf(b1.x, wreg[col][4],  acc[col]);                       \
        acc[col] = fmaf(b1.y, wreg[col][5],  acc[col]);                       \
        acc[col] = fmaf(b1.z, wreg[col][6],  acc[col]);                       \
        acc[col] = fmaf(b1.w, wreg[col][7],  acc[col]);                       \
        acc[col] = fmaf(b2.x, wreg[col][8],  acc[col]);                       \
        acc[col] = fmaf(b2.y, wreg[col][9],  acc[col]);                       \
        acc[col] = fmaf(b2.z, wreg[col][10], acc[col]);                       \
        acc[col] = fmaf(b2.w, wreg[col][11], acc[col]);                       \
      }                                                                       \
      _Pragma("unroll")                                                       \
      for (int c = 0; c < 13; ++c) {                                          \
        DPP_REDUCE64(acc[c])                                                  \
      }                                                                       \
      if (l == 63) {                                                          \
        _Pragma("unroll")                                                     \
        for (int c = 0; c < 13; ++c)                                          \
          fsT[c * 260 + r] = acc[c] + bs[c];                                  \
        asm volatile("s_waitcnt lgkmcnt(0)" ::: "memory");                    \
        flags[r] = 1;                                                         \
      }                                                                       \
    }

    #pragma unroll 4
    for (int i = 0; i < 36; ++i) {
      const int s = i & 3;
      PROW(i, s)
      {  // refill slot s with row i+4 (clamped; tail loads unused/duplicate)
        const int rn = pw + 7 * (i + 4);
        const int rc = (rn < 256) ? rn : 255;
        const float* xn = Xb + rc * 768;
        buf[s][0] = *reinterpret_cast<const float4*>(xn);
        buf[s][1] = *reinterpret_cast<const float4*>(xn + 256);
        buf[s][2] = *reinterpret_cast<const float4*>(xn + 512);
      }
    }
    if (pw < 4) {          // peeled i=36 (waves 1-4 own rows 252..255)
      PROW(36, 0)
    }
    #undef PROW
  }
  __syncthreads();

  // ================== phases 2-5 (verbatim r19, 512 threads) ================
  // ---- phase 2: psi in parallel over t (stride 32) ----
  {
    const int to = tid & 15, dtt = tid >> 4;   // dtt = 0..31
    if (to < 13) {
      float trr[13];
      #pragma unroll
      for (int f = 0; f < 13; ++f) trr[f] = trL[to * 13 + f];
      for (int t = (dtt == 0 ? 32 : dtt); t < 256; t += 32) {
        const float* lp = &lds_ld[(t - 1) * 16];
        float4 l0 = *reinterpret_cast<const float4*>(lp);
        float4 l1 = *reinterpret_cast<const float4*>(lp + 4);
        float4 l2 = *reinterpret_cast<const float4*>(lp + 8);
        float4 l3 = *reinterpret_cast<const float4*>(lp + 12);
        float c[13] = {trr[0] + l0.x,  trr[1] + l0.y,  trr[2] + l0.z,
                       trr[3] + l0.w,  trr[4] + l1.x,  trr[5] + l1.y,
                       trr[6] + l1.z,  trr[7] + l1.w,  trr[8] + l2.x,
                       trr[9] + l2.y,  trr[10] + l2.z, trr[11] + l2.w,
                       trr[12] + l3.x};
        float best = c[0]; int bf = 0;
        #pragma unroll
        for (int f = 1; f < 13; ++f) {
          bool gt = c[f] > best;              // strict >: first index wins
          best = gt ? c[f] : best;
          bf   = gt ? f : bf;
        }
        psi[t * 16 + to] = (unsigned char)bf;
      }
    }
  }
  __syncthreads();

  // ---- phase 3: ancestor maps (tid < 256) ----
  if (tid < 256) {
    const int sS = tid & 15, g = tid >> 4;
    if (sS < 13) {
      int cur = sS;
      const int tLo = (g == 0) ? 1 : g * 16;
      for (int t = g * 16 + 15; t >= tLo; --t)
        cur = psi[t * 16 + cur];
      Mm[g * 16 + sS] = (unsigned char)cur;
    }
  }
  __syncthreads();

  // ---- phase 4: softmax output + boundary chase ----
  if (tid == 0) {
    const float* lf = &lds_ld[255 * 16];
    float m = lf[0]; int last = 0;
    #pragma unroll
    for (int i = 1; i < 13; ++i)
      if (lf[i] > m) { m = lf[i]; last = i; }   // strict >: first index
    float ssum = 0.0f;
    #pragma unroll
    for (int i = 0; i < 13; ++i) ssum += expf(lf[i] - m);
    out[b] = 1.0f / (256.0f * ssum);            // max(softmax)/T

    int cur = last;
    bnd[15] = (unsigned char)cur;
    #pragma unroll
    for (int cc = 15; cc >= 1; --cc) {
      cur = Mm[cc * 16 + cur];
      bnd[cc - 1] = (unsigned char)cur;
    }
  }
  __syncthreads();

  // ---- phase 5: interior chases ----
  if (tid < 16) {
    int cur = bnd[tid];
    const int tHi = tid * 16 + 15;
    path[tHi] = (unsigned char)cur;
    const int tLo = (tid == 0) ? 1 : tid * 16;
    for (int t = tHi; t >= tLo; --t) {
      cur = psi[t * 16 + cur];
      path[t - 1] = (unsigned char)cur;
    }
  }
  __syncthreads();

  if (tid < 256)
    out[256 + (long)b * 256 + tid] = (float)path[tid];
}

// ------------------------------------------------------------------ launch --
extern "C" void kernel_launch(void* const* d_in, const int* in_sizes, int n_in,
                              void* d_out, int out_size, void* d_ws, size_t ws_size,
                              hipStream_t stream) {
  const float* X     = (const float*)d_in[0];
  const float* W     = (const float*)d_in[1];
  const float* bias  = (const float*)d_in[2];
  const float* trans = (const float*)d_in[3];
  float* out = (float*)d_out;

  fused_kernel<<<256, 512, 0, stream>>>(X, W, bias, trans, out);
}